// Round 1
// baseline (972.167 us; speedup 1.0000x reference)
//
#include <hip/hip_runtime.h>

#define LEAKY 0.2f

// ---------------------------------------------------------------- CSR build
__global__ __launch_bounds__(256) void hist_kernel(const int* __restrict__ row, int E,
                                                   int* __restrict__ deg) {
    int e = blockIdx.x * 256 + threadIdx.x;
    if (e < E) atomicAdd(&deg[row[e]], 1);
}

__global__ __launch_bounds__(1024) void scan_kernel(const int* __restrict__ deg,
                                                    int* __restrict__ rowptr, int n) {
    __shared__ int sums[1024];
    int tid = threadIdx.x;
    int chunk = (n + 1023) >> 10;
    int s0 = tid * chunk;
    int s1 = s0 + chunk; if (s1 > n) s1 = n;
    int sum = 0;
    for (int i = s0; i < s1; ++i) sum += deg[i];
    sums[tid] = sum;
    __syncthreads();
    int total = sum;
    for (int off = 1; off < 1024; off <<= 1) {
        int v = (tid >= off) ? sums[tid - off] : 0;
        __syncthreads();
        sums[tid] += v;
        __syncthreads();
    }
    int run = sums[tid] - total;  // exclusive prefix of this thread's chunk
    for (int i = s0; i < s1; ++i) { rowptr[i] = run; run += deg[i]; }
    if (tid == 1023) rowptr[n] = sums[1023];
}

__global__ __launch_bounds__(256) void dinv_kernel(const int* __restrict__ deg,
                                                   float* __restrict__ dinv, int n) {
    int i = blockIdx.x * 256 + threadIdx.x;
    if (i < n) {
        int d = deg[i];
        dinv[i] = d > 0 ? rsqrtf((float)d) : 0.0f;
    }
}

__global__ __launch_bounds__(256) void scatter_kernel(const int* __restrict__ row,
                                                      const int* __restrict__ col, int E,
                                                      const int* __restrict__ rowptr,
                                                      int* __restrict__ cursor,
                                                      const float* __restrict__ dinv,
                                                      int* __restrict__ cols_s,
                                                      float* __restrict__ norms_s) {
    int e = blockIdx.x * 256 + threadIdx.x;
    if (e < E) {
        int r = row[e], c = col[e];
        int p = rowptr[r] + atomicAdd(&cursor[r], 1);
        cols_s[p] = c;
        norms_s[p] = dinv[r] * dinv[c];
    }
}

// wt[layer][d][k] = w[layer][k][d]  (so W^T rows are contiguous for scalar loads)
__global__ __launch_bounds__(256) void wtrans_kernel(const float* __restrict__ w,
                                                     float* __restrict__ wt, int total) {
    int i = blockIdx.x * 256 + threadIdx.x;
    if (i < total) {
        int layer = i >> 12;
        int k = (i >> 6) & 63;
        int d = i & 63;
        wt[(layer << 12) + (d << 6) + k] = w[i];
    }
}

// ---------------------------------------------------------------- aggregate
// one wave per node, lane = feature dim; edge walk with wave-uniform scalar loads
__global__ __launch_bounds__(256) void aggregate_kernel(const int* __restrict__ rowptr,
                                                        const int* __restrict__ cols_s,
                                                        const float* __restrict__ norms_s,
                                                        const float* __restrict__ h_in,
                                                        int h_stride,
                                                        float* __restrict__ agg,
                                                        int n_nodes) {
    int lane = threadIdx.x & 63;
    int n = (blockIdx.x * blockDim.x + threadIdx.x) >> 6;
    if (n >= n_nodes) return;
    int nu = __builtin_amdgcn_readfirstlane(n);
    int s = rowptr[nu];
    int e = rowptr[nu + 1];
    float acc0 = 0.0f, acc1 = 0.0f;
    int t = s;
    for (; t + 1 < e; t += 2) {
        int c0 = cols_s[t];
        int c1 = cols_s[t + 1];
        float w0 = norms_s[t];
        float w1 = norms_s[t + 1];
        acc0 = fmaf(w0, h_in[(size_t)c0 * h_stride + lane], acc0);
        acc1 = fmaf(w1, h_in[(size_t)c1 * h_stride + lane], acc1);
    }
    if (t < e) {
        int c0 = cols_s[t];
        float w0 = norms_s[t];
        acc0 = fmaf(w0, h_in[(size_t)c0 * h_stride + lane], acc0);
    }
    agg[((size_t)n << 6) + lane] = acc0 + acc1;
}

// ---------------------------------------------------------------- transform
// thread-per-node; a[64], m[64] in VGPRs; W^T rows are wave-uniform -> s_load;
// 128 v_fmac per node via two independent acc chains; transpose via padded LDS.
__global__ __launch_bounds__(64) void transform_kernel(const float* __restrict__ h_in,
                                                       int h_stride,
                                                       const float* __restrict__ agg,
                                                       const float* __restrict__ wt1,
                                                       const float* __restrict__ b1,
                                                       const float* __restrict__ wt2,
                                                       const float* __restrict__ b2,
                                                       float* __restrict__ h_out,
                                                       int ostride, int n_nodes) {
    __shared__ float tile[64][65];
    int lane = threadIdx.x;
    int n = blockIdx.x * 64 + lane;
    float a[64], m[64];
    if (n < n_nodes) {
        const float4* ag4 = reinterpret_cast<const float4*>(agg + ((size_t)n << 6));
        const float* hrow = h_in + (size_t)n * h_stride;
#pragma unroll
        for (int j = 0; j < 16; ++j) {
            float4 av = ag4[j];
            float4 hv = *reinterpret_cast<const float4*>(hrow + j * 4);
            a[4 * j + 0] = av.x; a[4 * j + 1] = av.y;
            a[4 * j + 2] = av.z; a[4 * j + 3] = av.w;
            m[4 * j + 0] = av.x * hv.x; m[4 * j + 1] = av.y * hv.y;
            m[4 * j + 2] = av.z * hv.z; m[4 * j + 3] = av.w * hv.w;
        }
    } else {
#pragma unroll
        for (int k = 0; k < 64; ++k) { a[k] = 0.0f; m[k] = 0.0f; }
    }
    for (int d = 0; d < 64; ++d) {
        const float* w1r = wt1 + (d << 6);
        const float* w2r = wt2 + (d << 6);
        float acc1 = b1[d];
        float acc2 = b2[d];
#pragma unroll
        for (int k = 0; k < 64; ++k) {
            acc1 = fmaf(a[k], w1r[k], acc1);
            acc2 = fmaf(m[k], w2r[k], acc2);
        }
        float v1 = acc1 > 0.0f ? acc1 : LEAKY * acc1;
        float v2 = acc2 > 0.0f ? acc2 : LEAKY * acc2;
        tile[lane][d] = v1 + v2;
    }
    // flush transposed: coalesced 256B row stores
    int nb = blockIdx.x * 64;
    for (int r = 0; r < 64; ++r) {
        int node = nb + r;
        if (node < n_nodes) h_out[(size_t)node * ostride + lane] = tile[r][lane];
    }
}

// ---------------------------------------------------------------- finalize
// slot 0: copy x; slots 1..K: l2-normalize in place. one wave per (node, slot).
__global__ __launch_bounds__(256) void finalize_kernel(const float* __restrict__ x,
                                                       float* __restrict__ out,
                                                       int n_nodes, int nslots) {
    int lane = threadIdx.x & 63;
    int widx = (blockIdx.x * blockDim.x + threadIdx.x) >> 6;
    if (widx >= n_nodes * nslots) return;
    int node = widx / nslots;
    int slot = widx - node * nslots;
    size_t ostride = (size_t)nslots * 64;
    if (slot == 0) {
        out[(size_t)node * ostride + lane] = x[((size_t)node << 6) + lane];
    } else {
        float* p = out + (size_t)node * ostride + (size_t)slot * 64;
        float v = p[lane];
        float sq = v * v;
        for (int off = 32; off; off >>= 1) sq += __shfl_xor(sq, off, 64);
        float r = rsqrtf(fmaxf(sq, 1e-12f));
        p[lane] = v * r;
    }
}

// ---------------------------------------------------------------- launch
extern "C" void kernel_launch(void* const* d_in, const int* in_sizes, int n_in,
                              void* d_out, int out_size, void* d_ws, size_t ws_size,
                              hipStream_t stream) {
    const float* x  = (const float*)d_in[0];
    const int*  edge = (const int*)d_in[1];
    const float* W1 = (const float*)d_in[2];
    const float* b1 = (const float*)d_in[3];
    const float* W2 = (const float*)d_in[4];
    const float* b2 = (const float*)d_in[5];

    const int N = in_sizes[0] / 64;
    const int E = in_sizes[1] / 2;
    const int K = in_sizes[2] / 4096;
    const int nslots = K + 1;
    const int ostride = nslots * 64;

    const int* row = edge;
    const int* col = edge + E;
    float* out = (float*)d_out;

    // workspace carve-up (all 256B aligned)
    char* ws = (char*)d_ws;
    size_t off = 0;
    auto carve = [&](size_t bytes) -> void* {
        void* p = ws + off;
        off = (off + bytes + 255) & ~(size_t)255;
        return p;
    };
    int*   deg     = (int*)  carve((size_t)N * 4);
    int*   rowptr  = (int*)  carve((size_t)(N + 1) * 4);
    int*   cursor  = (int*)  carve((size_t)N * 4);
    float* dinv    = (float*)carve((size_t)N * 4);
    int*   cols_s  = (int*)  carve((size_t)E * 4);
    float* norms_s = (float*)carve((size_t)E * 4);
    float* agg     = (float*)carve((size_t)N * 64 * 4);
    float* wt1     = (float*)carve((size_t)K * 4096 * 4);
    float* wt2     = (float*)carve((size_t)K * 4096 * 4);
    (void)ws_size;

    hipMemsetAsync(deg, 0, (size_t)N * 4, stream);
    hipMemsetAsync(cursor, 0, (size_t)N * 4, stream);

    hist_kernel<<<(E + 255) / 256, 256, 0, stream>>>(row, E, deg);
    scan_kernel<<<1, 1024, 0, stream>>>(deg, rowptr, N);
    dinv_kernel<<<(N + 255) / 256, 256, 0, stream>>>(deg, dinv, N);
    scatter_kernel<<<(E + 255) / 256, 256, 0, stream>>>(row, col, E, rowptr, cursor, dinv,
                                                        cols_s, norms_s);
    wtrans_kernel<<<(K * 4096 + 255) / 256, 256, 0, stream>>>(W1, wt1, K * 4096);
    wtrans_kernel<<<(K * 4096 + 255) / 256, 256, 0, stream>>>(W2, wt2, K * 4096);

    for (int i = 0; i < K; ++i) {
        const float* h_in = (i == 0) ? x : (out + (size_t)i * 64);
        int h_stride = (i == 0) ? 64 : ostride;
        aggregate_kernel<<<(N * 64 + 255) / 256, 256, 0, stream>>>(rowptr, cols_s, norms_s,
                                                                   h_in, h_stride, agg, N);
        transform_kernel<<<(N + 63) / 64, 64, 0, stream>>>(h_in, h_stride, agg,
                                                           wt1 + (size_t)i * 4096,
                                                           b1 + (size_t)i * 64,
                                                           wt2 + (size_t)i * 4096,
                                                           b2 + (size_t)i * 64,
                                                           out + (size_t)(i + 1) * 64,
                                                           ostride, N);
    }

    int total_waves = N * nslots;
    finalize_kernel<<<(total_waves * 64 + 255) / 256, 256, 0, stream>>>(x, out, N, nslots);
}

// Round 2
// 630.834 us; speedup vs baseline: 1.5411x; 1.5411x over previous
//
#include <hip/hip_runtime.h>

#define LEAKY 0.2f

__device__ __forceinline__ float lane_bcast(float v, int k) {
    return __int_as_float(__builtin_amdgcn_readlane(__float_as_int(v), k));
}

// ---------------------------------------------------------------- CSR build
__global__ __launch_bounds__(256) void hist_kernel(const int* __restrict__ row, int E,
                                                   int* __restrict__ deg) {
    int e = blockIdx.x * 256 + threadIdx.x;
    if (e < E) atomicAdd(&deg[row[e]], 1);
}

__global__ __launch_bounds__(1024) void scan_kernel(const int* __restrict__ deg,
                                                    int* __restrict__ rowptr, int n) {
    __shared__ int sums[1024];
    int tid = threadIdx.x;
    int chunk = (n + 1023) >> 10;
    int s0 = tid * chunk;
    int s1 = s0 + chunk; if (s1 > n) s1 = n;
    int sum = 0;
    for (int i = s0; i < s1; ++i) sum += deg[i];
    sums[tid] = sum;
    __syncthreads();
    int total = sum;
    for (int off = 1; off < 1024; off <<= 1) {
        int v = (tid >= off) ? sums[tid - off] : 0;
        __syncthreads();
        sums[tid] += v;
        __syncthreads();
    }
    int run = sums[tid] - total;  // exclusive prefix of this thread's chunk
    for (int i = s0; i < s1; ++i) { rowptr[i] = run; run += deg[i]; }
    if (tid == 1023) rowptr[n] = sums[1023];
}

__global__ __launch_bounds__(256) void dinv_kernel(const int* __restrict__ deg,
                                                   float* __restrict__ dinv, int n) {
    int i = blockIdx.x * 256 + threadIdx.x;
    if (i < n) {
        int d = deg[i];
        dinv[i] = d > 0 ? rsqrtf((float)d) : 0.0f;
    }
}

__global__ __launch_bounds__(256) void scatter_kernel(const int* __restrict__ row,
                                                      const int* __restrict__ col, int E,
                                                      const int* __restrict__ rowptr,
                                                      int* __restrict__ cursor,
                                                      const float* __restrict__ dinv,
                                                      int* __restrict__ cols_s,
                                                      float* __restrict__ norms_s) {
    int e = blockIdx.x * 256 + threadIdx.x;
    if (e < E) {
        int r = row[e], c = col[e];
        int p = rowptr[r] + atomicAdd(&cursor[r], 1);
        cols_s[p] = c;
        norms_s[p] = dinv[r] * dinv[c];
    }
}

// ---------------------------------------------------------------- aggregate
// one wave per node, lane = feature dim; 4 independent acc chains keep 4
// row-gathers in flight (latency-bound on L2/L3).
__global__ __launch_bounds__(256) void aggregate_kernel(const int* __restrict__ rowptr,
                                                        const int* __restrict__ cols_s,
                                                        const float* __restrict__ norms_s,
                                                        const float* __restrict__ h_in,
                                                        int h_stride,
                                                        float* __restrict__ agg,
                                                        int n_nodes) {
    int lane = threadIdx.x & 63;
    int n = (blockIdx.x * blockDim.x + threadIdx.x) >> 6;
    if (n >= n_nodes) return;
    int nu = __builtin_amdgcn_readfirstlane(n);
    int s = rowptr[nu];
    int e = rowptr[nu + 1];
    float acc0 = 0.0f, acc1 = 0.0f, acc2 = 0.0f, acc3 = 0.0f;
    int t = s;
    for (; t + 3 < e; t += 4) {
        int c0 = cols_s[t + 0];
        int c1 = cols_s[t + 1];
        int c2 = cols_s[t + 2];
        int c3 = cols_s[t + 3];
        float w0 = norms_s[t + 0];
        float w1 = norms_s[t + 1];
        float w2 = norms_s[t + 2];
        float w3 = norms_s[t + 3];
        acc0 = fmaf(w0, h_in[(size_t)c0 * h_stride + lane], acc0);
        acc1 = fmaf(w1, h_in[(size_t)c1 * h_stride + lane], acc1);
        acc2 = fmaf(w2, h_in[(size_t)c2 * h_stride + lane], acc2);
        acc3 = fmaf(w3, h_in[(size_t)c3 * h_stride + lane], acc3);
    }
    for (; t < e; ++t) {
        acc0 = fmaf(norms_s[t], h_in[(size_t)cols_s[t] * h_stride + lane], acc0);
    }
    agg[((size_t)n << 6) + lane] = (acc0 + acc1) + (acc2 + acc3);
}

// ---------------------------------------------------------------- transform
// lane = output dim d. W1/W2 columns live in VGPRs (w1r[k] = W1[k][lane]),
// loaded once per wave. Per node: coalesced loads of agg/h rows (lane = k),
// broadcast a_k via v_readlane, 128 fmas into 2 independent acc chains.
// No LDS, no SMEM in the hot loop, stores coalesced.
#define NODES_PER_WAVE 16
__global__ __launch_bounds__(256, 3) void transform_kernel(const float* __restrict__ h_in,
                                                           int h_stride,
                                                           const float* __restrict__ agg,
                                                           const float* __restrict__ w1,
                                                           const float* __restrict__ b1,
                                                           const float* __restrict__ w2,
                                                           const float* __restrict__ b2,
                                                           float* __restrict__ h_out,
                                                           int ostride, int n_nodes) {
    int lane = threadIdx.x & 63;
    int wave = (blockIdx.x * blockDim.x + threadIdx.x) >> 6;

    float w1r[64], w2r[64];
#pragma unroll 64
    for (int k = 0; k < 64; ++k) {
        w1r[k] = w1[(k << 6) + lane];   // W1[k][d=lane], coalesced, L2-hot
        w2r[k] = w2[(k << 6) + lane];
    }
    float b1v = b1[lane];
    float b2v = b2[lane];

    int n0 = wave * NODES_PER_WAVE;
#pragma unroll 1
    for (int ni = 0; ni < NODES_PER_WAVE; ++ni) {
        int n = n0 + ni;
        if (n >= n_nodes) break;
        float av = agg[((size_t)n << 6) + lane];          // lane = k role
        float hv = h_in[(size_t)n * h_stride + lane];
        float mv = av * hv;
        float acc1 = b1v;
        float acc2 = b2v;
#pragma unroll 64
        for (int k = 0; k < 64; ++k) {
            acc1 = fmaf(lane_bcast(av, k), w1r[k], acc1);
            acc2 = fmaf(lane_bcast(mv, k), w2r[k], acc2);
        }
        float v1 = acc1 > 0.0f ? acc1 : LEAKY * acc1;
        float v2 = acc2 > 0.0f ? acc2 : LEAKY * acc2;
        h_out[(size_t)n * ostride + lane] = v1 + v2;      // lane = d role
    }
}

// ---------------------------------------------------------------- finalize
// slot 0: copy x; slots 1..K: l2-normalize in place. one wave per (node, slot).
__global__ __launch_bounds__(256) void finalize_kernel(const float* __restrict__ x,
                                                       float* __restrict__ out,
                                                       int n_nodes, int nslots) {
    int lane = threadIdx.x & 63;
    int widx = (blockIdx.x * blockDim.x + threadIdx.x) >> 6;
    if (widx >= n_nodes * nslots) return;
    int node = widx / nslots;
    int slot = widx - node * nslots;
    size_t ostride = (size_t)nslots * 64;
    if (slot == 0) {
        out[(size_t)node * ostride + lane] = x[((size_t)node << 6) + lane];
    } else {
        float* p = out + (size_t)node * ostride + (size_t)slot * 64;
        float v = p[lane];
        float sq = v * v;
        for (int off = 32; off; off >>= 1) sq += __shfl_xor(sq, off, 64);
        float r = rsqrtf(fmaxf(sq, 1e-12f));
        p[lane] = v * r;
    }
}

// ---------------------------------------------------------------- launch
extern "C" void kernel_launch(void* const* d_in, const int* in_sizes, int n_in,
                              void* d_out, int out_size, void* d_ws, size_t ws_size,
                              hipStream_t stream) {
    const float* x  = (const float*)d_in[0];
    const int*  edge = (const int*)d_in[1];
    const float* W1 = (const float*)d_in[2];
    const float* b1 = (const float*)d_in[3];
    const float* W2 = (const float*)d_in[4];
    const float* b2 = (const float*)d_in[5];

    const int N = in_sizes[0] / 64;
    const int E = in_sizes[1] / 2;
    const int K = in_sizes[2] / 4096;
    const int nslots = K + 1;
    const int ostride = nslots * 64;

    const int* row = edge;
    const int* col = edge + E;
    float* out = (float*)d_out;

    // workspace carve-up (all 256B aligned)
    char* ws = (char*)d_ws;
    size_t off = 0;
    auto carve = [&](size_t bytes) -> void* {
        void* p = ws + off;
        off = (off + bytes + 255) & ~(size_t)255;
        return p;
    };
    int*   deg     = (int*)  carve((size_t)N * 4);
    int*   rowptr  = (int*)  carve((size_t)(N + 1) * 4);
    int*   cursor  = (int*)  carve((size_t)N * 4);
    float* dinv    = (float*)carve((size_t)N * 4);
    int*   cols_s  = (int*)  carve((size_t)E * 4);
    float* norms_s = (float*)carve((size_t)E * 4);
    float* agg     = (float*)carve((size_t)N * 64 * 4);
    (void)ws_size;

    hipMemsetAsync(deg, 0, (size_t)N * 4, stream);
    hipMemsetAsync(cursor, 0, (size_t)N * 4, stream);

    hist_kernel<<<(E + 255) / 256, 256, 0, stream>>>(row, E, deg);
    scan_kernel<<<1, 1024, 0, stream>>>(deg, rowptr, N);
    dinv_kernel<<<(N + 255) / 256, 256, 0, stream>>>(deg, dinv, N);
    scatter_kernel<<<(E + 255) / 256, 256, 0, stream>>>(row, col, E, rowptr, cursor, dinv,
                                                        cols_s, norms_s);

    const int waves_needed = (N + NODES_PER_WAVE - 1) / NODES_PER_WAVE;
    const int tblocks = (waves_needed + 3) / 4;

    for (int i = 0; i < K; ++i) {
        const float* h_in = (i == 0) ? x : (out + (size_t)i * 64);
        int h_stride = (i == 0) ? 64 : ostride;
        aggregate_kernel<<<(N * 64 + 255) / 256, 256, 0, stream>>>(rowptr, cols_s, norms_s,
                                                                   h_in, h_stride, agg, N);
        transform_kernel<<<tblocks, 256, 0, stream>>>(h_in, h_stride, agg,
                                                      W1 + (size_t)i * 4096,
                                                      b1 + (size_t)i * 64,
                                                      W2 + (size_t)i * 4096,
                                                      b2 + (size_t)i * 64,
                                                      out + (size_t)(i + 1) * 64,
                                                      ostride, N);
    }

    int total_waves = N * nslots;
    finalize_kernel<<<(total_waves * 64 + 255) / 256, 256, 0, stream>>>(x, out, N, nslots);
}

// Round 3
// 482.819 us; speedup vs baseline: 2.0135x; 1.3066x over previous
//
#include <hip/hip_runtime.h>

#define LEAKY 0.2f
#define SCAN_BS 256

__device__ __forceinline__ float lane_bcast(float v, int k) {
    return __int_as_float(__builtin_amdgcn_readlane(__float_as_int(v), k));
}

// ---------------------------------------------------------------- CSR build
__global__ __launch_bounds__(256) void hist_kernel(const int* __restrict__ row, int E,
                                                   int* __restrict__ deg) {
    int e = blockIdx.x * 256 + threadIdx.x;
    if (e < E) atomicAdd(&deg[row[e]], 1);
}

// phase 1: per-block sums of deg
__global__ __launch_bounds__(SCAN_BS) void bsum_kernel(const int* __restrict__ deg,
                                                       int* __restrict__ bsums, int n) {
    int i = blockIdx.x * SCAN_BS + threadIdx.x;
    int v = (i < n) ? deg[i] : 0;
    for (int off = 32; off; off >>= 1) v += __shfl_xor(v, off, 64);
    __shared__ int wsum[SCAN_BS / 64];
    int lane = threadIdx.x & 63, w = threadIdx.x >> 6;
    if (lane == 0) wsum[w] = v;
    __syncthreads();
    if (threadIdx.x == 0) {
        int s = 0;
#pragma unroll
        for (int j = 0; j < SCAN_BS / 64; ++j) s += wsum[j];
        bsums[blockIdx.x] = s;
    }
}

// phase 2: exclusive scan of block sums (nb <= 1024), single small block
__global__ __launch_bounds__(1024) void scan_bsums_kernel(int* __restrict__ bsums, int nb) {
    __shared__ int sh[1024];
    int tid = threadIdx.x;
    int v = (tid < nb) ? bsums[tid] : 0;
    sh[tid] = v;
    __syncthreads();
    for (int off = 1; off < 1024; off <<= 1) {
        int u = (tid >= off) ? sh[tid - off] : 0;
        __syncthreads();
        sh[tid] += u;
        __syncthreads();
    }
    if (tid < nb) bsums[tid] = sh[tid] - v;  // exclusive
}

// phase 3: in-block exclusive scan + block base; grid covers n+1 so rowptr[n]=E
__global__ __launch_bounds__(SCAN_BS) void rowptr_kernel(const int* __restrict__ deg,
                                                         const int* __restrict__ bsums_ex,
                                                         int* __restrict__ rowptr, int n) {
    __shared__ int sh[SCAN_BS];
    int tid = threadIdx.x;
    int i = blockIdx.x * SCAN_BS + tid;
    int v = (i < n) ? deg[i] : 0;
    sh[tid] = v;
    __syncthreads();
    for (int off = 1; off < SCAN_BS; off <<= 1) {
        int u = (tid >= off) ? sh[tid - off] : 0;
        __syncthreads();
        sh[tid] += u;
        __syncthreads();
    }
    if (i <= n) rowptr[i] = sh[tid] - v + bsums_ex[blockIdx.x];
}

__global__ __launch_bounds__(256) void dinv_kernel(const int* __restrict__ deg,
                                                   float* __restrict__ dinv, int n) {
    int i = blockIdx.x * 256 + threadIdx.x;
    if (i < n) {
        int d = deg[i];
        dinv[i] = d > 0 ? rsqrtf((float)d) : 0.0f;
    }
}

__global__ __launch_bounds__(256) void scatter_kernel(const int* __restrict__ row,
                                                      const int* __restrict__ col, int E,
                                                      const int* __restrict__ rowptr,
                                                      int* __restrict__ cursor,
                                                      const float* __restrict__ dinv,
                                                      int* __restrict__ cols_s,
                                                      float* __restrict__ norms_s) {
    int e = blockIdx.x * 256 + threadIdx.x;
    if (e < E) {
        int r = row[e], c = col[e];
        int p = rowptr[r] + atomicAdd(&cursor[r], 1);
        cols_s[p] = c;
        norms_s[p] = dinv[r] * dinv[c];
    }
}

// ---------------------------------------------------------------- aggregate
// one wave per node, lane = feature dim; 4 independent acc chains keep 4
// row-gathers in flight (latency-bound on L2/L3).
__global__ __launch_bounds__(256) void aggregate_kernel(const int* __restrict__ rowptr,
                                                        const int* __restrict__ cols_s,
                                                        const float* __restrict__ norms_s,
                                                        const float* __restrict__ h_in,
                                                        int h_stride,
                                                        float* __restrict__ agg,
                                                        int n_nodes) {
    int lane = threadIdx.x & 63;
    int n = (blockIdx.x * blockDim.x + threadIdx.x) >> 6;
    if (n >= n_nodes) return;
    int nu = __builtin_amdgcn_readfirstlane(n);
    int s = rowptr[nu];
    int e = rowptr[nu + 1];
    float acc0 = 0.0f, acc1 = 0.0f, acc2 = 0.0f, acc3 = 0.0f;
    int t = s;
    for (; t + 3 < e; t += 4) {
        int c0 = cols_s[t + 0];
        int c1 = cols_s[t + 1];
        int c2 = cols_s[t + 2];
        int c3 = cols_s[t + 3];
        float w0 = norms_s[t + 0];
        float w1 = norms_s[t + 1];
        float w2 = norms_s[t + 2];
        float w3 = norms_s[t + 3];
        acc0 = fmaf(w0, h_in[(size_t)c0 * h_stride + lane], acc0);
        acc1 = fmaf(w1, h_in[(size_t)c1 * h_stride + lane], acc1);
        acc2 = fmaf(w2, h_in[(size_t)c2 * h_stride + lane], acc2);
        acc3 = fmaf(w3, h_in[(size_t)c3 * h_stride + lane], acc3);
    }
    for (; t < e; ++t) {
        acc0 = fmaf(norms_s[t], h_in[(size_t)cols_s[t] * h_stride + lane], acc0);
    }
    agg[((size_t)n << 6) + lane] = (acc0 + acc1) + (acc2 + acc3);
}

// ---------------------------------------------------------------- transform
// lane = output dim d. W1/W2 columns live in VGPRs (w1r[k] = W1[k][lane]),
// loaded once per wave. Per node: coalesced loads of agg/h rows (lane = k),
// broadcast a_k via v_readlane, 128 fmas into 2 independent acc chains.
#define NODES_PER_WAVE 16
__global__ __launch_bounds__(256, 3) void transform_kernel(const float* __restrict__ h_in,
                                                           int h_stride,
                                                           const float* __restrict__ agg,
                                                           const float* __restrict__ w1,
                                                           const float* __restrict__ b1,
                                                           const float* __restrict__ w2,
                                                           const float* __restrict__ b2,
                                                           float* __restrict__ h_out,
                                                           int ostride, int n_nodes) {
    int lane = threadIdx.x & 63;
    int wave = (blockIdx.x * blockDim.x + threadIdx.x) >> 6;

    float w1r[64], w2r[64];
#pragma unroll 64
    for (int k = 0; k < 64; ++k) {
        w1r[k] = w1[(k << 6) + lane];   // W1[k][d=lane], coalesced, L2-hot
        w2r[k] = w2[(k << 6) + lane];
    }
    float b1v = b1[lane];
    float b2v = b2[lane];

    int n0 = wave * NODES_PER_WAVE;
#pragma unroll 1
    for (int ni = 0; ni < NODES_PER_WAVE; ++ni) {
        int n = n0 + ni;
        if (n >= n_nodes) break;
        float av = agg[((size_t)n << 6) + lane];          // lane = k role
        float hv = h_in[(size_t)n * h_stride + lane];
        float mv = av * hv;
        float acc1 = b1v;
        float acc2 = b2v;
#pragma unroll 64
        for (int k = 0; k < 64; ++k) {
            acc1 = fmaf(lane_bcast(av, k), w1r[k], acc1);
            acc2 = fmaf(lane_bcast(mv, k), w2r[k], acc2);
        }
        float v1 = acc1 > 0.0f ? acc1 : LEAKY * acc1;
        float v2 = acc2 > 0.0f ? acc2 : LEAKY * acc2;
        h_out[(size_t)n * ostride + lane] = v1 + v2;      // lane = d role
    }
}

// ---------------------------------------------------------------- finalize
__global__ __launch_bounds__(256) void finalize_kernel(const float* __restrict__ x,
                                                       float* __restrict__ out,
                                                       int n_nodes, int nslots) {
    int lane = threadIdx.x & 63;
    int widx = (blockIdx.x * blockDim.x + threadIdx.x) >> 6;
    if (widx >= n_nodes * nslots) return;
    int node = widx / nslots;
    int slot = widx - node * nslots;
    size_t ostride = (size_t)nslots * 64;
    if (slot == 0) {
        out[(size_t)node * ostride + lane] = x[((size_t)node << 6) + lane];
    } else {
        float* p = out + (size_t)node * ostride + (size_t)slot * 64;
        float v = p[lane];
        float sq = v * v;
        for (int off = 32; off; off >>= 1) sq += __shfl_xor(sq, off, 64);
        float r = rsqrtf(fmaxf(sq, 1e-12f));
        p[lane] = v * r;
    }
}

// ---------------------------------------------------------------- launch
extern "C" void kernel_launch(void* const* d_in, const int* in_sizes, int n_in,
                              void* d_out, int out_size, void* d_ws, size_t ws_size,
                              hipStream_t stream) {
    const float* x  = (const float*)d_in[0];
    const int*  edge = (const int*)d_in[1];
    const float* W1 = (const float*)d_in[2];
    const float* b1 = (const float*)d_in[3];
    const float* W2 = (const float*)d_in[4];
    const float* b2 = (const float*)d_in[5];

    const int N = in_sizes[0] / 64;
    const int E = in_sizes[1] / 2;
    const int K = in_sizes[2] / 4096;
    const int nslots = K + 1;
    const int ostride = nslots * 64;

    const int* row = edge;
    const int* col = edge + E;
    float* out = (float*)d_out;

    // workspace carve-up (all 256B aligned)
    char* ws = (char*)d_ws;
    size_t off = 0;
    auto carve = [&](size_t bytes) -> void* {
        void* p = ws + off;
        off = (off + bytes + 255) & ~(size_t)255;
        return p;
    };
    int*   deg     = (int*)  carve((size_t)N * 4);
    int*   rowptr  = (int*)  carve((size_t)(N + 1) * 4);
    int*   cursor  = (int*)  carve((size_t)N * 4);
    float* dinv    = (float*)carve((size_t)N * 4);
    int*   cols_s  = (int*)  carve((size_t)E * 4);
    float* norms_s = (float*)carve((size_t)E * 4);
    float* agg     = (float*)carve((size_t)N * 64 * 4);
    int*   bsums   = (int*)  carve(2048 * 4);
    (void)ws_size;

    hipMemsetAsync(deg, 0, (size_t)N * 4, stream);
    hipMemsetAsync(cursor, 0, (size_t)N * 4, stream);

    hist_kernel<<<(E + 255) / 256, 256, 0, stream>>>(row, E, deg);

    // hierarchical exclusive scan: deg -> rowptr (grid covers N+1 for rowptr[N]=E)
    const int nb = (N + 1 + SCAN_BS - 1) / SCAN_BS;   // 392 for N=100000
    bsum_kernel<<<nb, SCAN_BS, 0, stream>>>(deg, bsums, N);
    scan_bsums_kernel<<<1, 1024, 0, stream>>>(bsums, nb);
    rowptr_kernel<<<nb, SCAN_BS, 0, stream>>>(deg, bsums, rowptr, N);

    dinv_kernel<<<(N + 255) / 256, 256, 0, stream>>>(deg, dinv, N);
    scatter_kernel<<<(E + 255) / 256, 256, 0, stream>>>(row, col, E, rowptr, cursor, dinv,
                                                        cols_s, norms_s);

    const int waves_needed = (N + NODES_PER_WAVE - 1) / NODES_PER_WAVE;
    const int tblocks = (waves_needed + 3) / 4;

    for (int i = 0; i < K; ++i) {
        const float* h_in = (i == 0) ? x : (out + (size_t)i * 64);
        int h_stride = (i == 0) ? 64 : ostride;
        aggregate_kernel<<<(N * 64 + 255) / 256, 256, 0, stream>>>(rowptr, cols_s, norms_s,
                                                                   h_in, h_stride, agg, N);
        transform_kernel<<<tblocks, 256, 0, stream>>>(h_in, h_stride, agg,
                                                      W1 + (size_t)i * 4096,
                                                      b1 + (size_t)i * 64,
                                                      W2 + (size_t)i * 4096,
                                                      b2 + (size_t)i * 64,
                                                      out + (size_t)(i + 1) * 64,
                                                      ostride, N);
    }

    int total_waves = N * nslots;
    finalize_kernel<<<(total_waves * 64 + 255) / 256, 256, 0, stream>>>(x, out, N, nslots);
}